// Round 6
// baseline (1168.741 us; speedup 1.0000x reference)
//
#include <hip/hip_runtime.h>

#define N_USER 50000
#define N_ITEM 50000
#define N_NODE 50000
#define N_EDGE 1600000
#define D 64

#define FB_SHIFT 7        // 128 nodes per fine bucket
#define N_FINE 400        // covers 51200 >= 50000 nodes
#define CAP 5120          // per-bucket edge capacity (mean 4096, sigma 64 -> 16 sigma)
#define CHUNK 8192        // edges per fine_bin block

__device__ __forceinline__ unsigned short f32_to_bf16(float x) {
    unsigned u = __float_as_uint(x);
    unsigned r = (u + 0x7FFFu + ((u >> 16) & 1u)) >> 16;   // RNE
    return (unsigned short)r;
}
__device__ __forceinline__ float bf16_to_f32(unsigned short h) {
    return __uint_as_float(((unsigned)h) << 16);
}

// ---------------------------------------------------------------------------
// Kernel 0: fp32 -> bf16 feature table cast (halves gather traffic).
// ---------------------------------------------------------------------------
__global__ __launch_bounds__(256) void cast_kernel(
    const float4* __restrict__ in, ushort4* __restrict__ out, int n4)
{
    int i = blockIdx.x * 256 + threadIdx.x;
    if (i < n4) {
        float4 v = in[i];
        ushort4 o;
        o.x = f32_to_bf16(v.x); o.y = f32_to_bf16(v.y);
        o.z = f32_to_bf16(v.z); o.w = f32_to_bf16(v.w);
        out[i] = o;
    }
}

// ---------------------------------------------------------------------------
// Kernel 1: init per-bucket cursors to fixed bases f*CAP (replaces
// fhist+fscan+memset: fixed-capacity buckets need no global count pass).
// ---------------------------------------------------------------------------
__global__ __launch_bounds__(1024) void init_fcur(int* __restrict__ fcur)
{
    int i = threadIdx.x;
    if (i < 2 * N_FINE) {
        int f = (i < N_FINE) ? i : i - N_FINE;
        fcur[i] = f * CAP;
    }
}

// ---------------------------------------------------------------------------
// Kernel 2: fine binning (multisplit). Count chunk in LDS, reserve one
// contiguous window per bucket, scatter packed (dst<<16)|src via LDS cursors.
// Bucket f's window lives at [f*CAP, fcur[f]) after this kernel.
// ---------------------------------------------------------------------------
__global__ __launch_bounds__(256) void fine_bin(
    const int* __restrict__ srcA, const int* __restrict__ dstA, unsigned* __restrict__ binA,
    const int* __restrict__ srcB, const int* __restrict__ dstB, unsigned* __restrict__ binB,
    int* __restrict__ fcur)
{
    const int et = blockIdx.y;
    const int* __restrict__ src = et ? srcB : srcA;
    const int* __restrict__ dst = et ? dstB : dstA;
    unsigned* __restrict__ bin  = et ? binB : binA;
    int* __restrict__ fc = fcur + et * N_FINE;

    __shared__ int hist[N_FINE];
    __shared__ int lcur[N_FINE];
    for (int i = threadIdx.x; i < N_FINE; i += 256) hist[i] = 0;
    __syncthreads();

    const int base = blockIdx.x * CHUNK;
    const int n4 = (min(CHUNK, N_EDGE - base)) >> 2;   // N_EDGE % 4 == 0
    const int4* dst4 = (const int4*)(dst + base);
    const int4* src4 = (const int4*)(src + base);

    for (int i = threadIdx.x; i < n4; i += 256) {
        int4 d = dst4[i];
        atomicAdd(&hist[d.x >> FB_SHIFT], 1);
        atomicAdd(&hist[d.y >> FB_SHIFT], 1);
        atomicAdd(&hist[d.z >> FB_SHIFT], 1);
        atomicAdd(&hist[d.w >> FB_SHIFT], 1);
    }
    __syncthreads();
    for (int f = threadIdx.x; f < N_FINE; f += 256) {
        int c = hist[f];
        lcur[f] = c ? atomicAdd(&fc[f], c) : 0;
    }
    __syncthreads();
    for (int i = threadIdx.x; i < n4; i += 256) {
        int4 d = dst4[i];
        int4 s = src4[i];
        { int pos = atomicAdd(&lcur[d.x >> FB_SHIFT], 1); bin[pos] = ((unsigned)d.x << 16) | (unsigned)s.x; }
        { int pos = atomicAdd(&lcur[d.y >> FB_SHIFT], 1); bin[pos] = ((unsigned)d.y << 16) | (unsigned)s.y; }
        { int pos = atomicAdd(&lcur[d.z >> FB_SHIFT], 1); bin[pos] = ((unsigned)d.z << 16) | (unsigned)s.z; }
        { int pos = atomicAdd(&lcur[d.w >> FB_SHIFT], 1); bin[pos] = ((unsigned)d.w << 16) | (unsigned)s.w; }
    }
}

// ---------------------------------------------------------------------------
// Kernel 3: per-bucket counting sort. One block per fine bucket: count per
// node in LDS (1.5 KB only -> high occupancy), scan 128, emit absolute
// off[] + cnt[], scatter u16 src into the bucket's private srt window.
// ---------------------------------------------------------------------------
__global__ __launch_bounds__(256) void bucket_sort(
    const unsigned* __restrict__ binI, unsigned short* __restrict__ srtI,
    int* __restrict__ offI, int* __restrict__ cntI,
    const unsigned* __restrict__ binU, unsigned short* __restrict__ srtU,
    int* __restrict__ offU, int* __restrict__ cntU,
    const int* __restrict__ fcur)
{
    const int et = blockIdx.y;
    const unsigned* __restrict__ bin = et ? binU : binI;
    unsigned short* __restrict__ srt = et ? srtU : srtI;
    int* __restrict__ off  = et ? offU : offI;
    int* __restrict__ cntG = et ? cntU : cntI;
    const int f = blockIdx.x;
    const int start = f * CAP;
    const int end   = fcur[et * N_FINE + f];
    const int nodebase = f << FB_SHIFT;

    __shared__ int cnt[128];
    __shared__ int sc[128];
    __shared__ int pos[128];
    if (threadIdx.x < 128) cnt[threadIdx.x] = 0;
    __syncthreads();

    for (int e = start + threadIdx.x; e < end; e += 256) {
        int ld = (int)(bin[e] >> 16) - nodebase;
        atomicAdd(&cnt[ld], 1);
    }
    __syncthreads();

    if (threadIdx.x < 128) sc[threadIdx.x] = cnt[threadIdx.x];
    __syncthreads();
    for (int o = 1; o < 128; o <<= 1) {
        int t = 0;
        if (threadIdx.x < 128 && threadIdx.x >= o) t = sc[threadIdx.x - o];
        __syncthreads();
        if (threadIdx.x < 128) sc[threadIdx.x] += t;
        __syncthreads();
    }
    if (threadIdx.x < 128) {
        int base = start + sc[threadIdx.x] - cnt[threadIdx.x];   // absolute excl
        pos[threadIdx.x] = base;
        int node = nodebase + threadIdx.x;
        if (node < N_NODE) { off[node] = base; cntG[node] = cnt[threadIdx.x]; }
    }
    __syncthreads();

    for (int e = start + threadIdx.x; e < end; e += 256) {
        unsigned p = bin[e];
        int ld = (int)(p >> 16) - nodebase;
        int q = atomicAdd(&pos[ld], 1);
        srt[q] = (unsigned short)(p & 0xFFFFu);
    }
}

// ---------------------------------------------------------------------------
// Kernel 4: raw-feature segment mean (bf16 gather). Round-4 shape: no LDS,
// 16 lanes per dst node, ushort4 per lane (128 B per edge), unroll-2.
// ---------------------------------------------------------------------------
__global__ __launch_bounds__(256) void aggregate_kernel(
    const ushort4* __restrict__ itemB,   // sources for user dst (rev)
    const ushort4* __restrict__ userB,   // sources for item dst (rate)
    const int* __restrict__ offU, const int* __restrict__ cntU, const unsigned short* __restrict__ srtU,
    const int* __restrict__ offI, const int* __restrict__ cntI, const unsigned short* __restrict__ srtI,
    ushort4* __restrict__ aggU, ushort4* __restrict__ aggI)
{
    int g = blockIdx.x * 16 + (threadIdx.x >> 4);
    if (g >= N_USER + N_ITEM) return;
    const int lane = threadIdx.x & 15;

    const bool isUser = (g < N_USER);
    const int d = isUser ? g : g - N_USER;
    const ushort4* __restrict__ tab = isUser ? itemB : userB;
    const int* __restrict__ off     = isUser ? offU : offI;
    const int* __restrict__ cntG    = isUser ? cntU : cntI;
    const unsigned short* __restrict__ srt = isUser ? srtU : srtI;
    ushort4* __restrict__ agg       = isUser ? aggU : aggI;

    const int start = off[d];
    const int c     = cntG[d];
    const int end   = start + c;

    float4 a0 = make_float4(0.f, 0.f, 0.f, 0.f);
    float4 a1 = make_float4(0.f, 0.f, 0.f, 0.f);
    int e = start;
    for (; e + 2 <= end; e += 2) {
        int s0 = (int)srt[e], s1 = (int)srt[e + 1];
        ushort4 w0 = tab[(size_t)s0 * 16 + lane];
        ushort4 w1 = tab[(size_t)s1 * 16 + lane];
        a0.x += bf16_to_f32(w0.x); a0.y += bf16_to_f32(w0.y);
        a0.z += bf16_to_f32(w0.z); a0.w += bf16_to_f32(w0.w);
        a1.x += bf16_to_f32(w1.x); a1.y += bf16_to_f32(w1.y);
        a1.z += bf16_to_f32(w1.z); a1.w += bf16_to_f32(w1.w);
    }
    if (e < end) {
        int s0 = (int)srt[e];
        ushort4 w0 = tab[(size_t)s0 * 16 + lane];
        a0.x += bf16_to_f32(w0.x); a0.y += bf16_to_f32(w0.y);
        a0.z += bf16_to_f32(w0.z); a0.w += bf16_to_f32(w0.w);
    }
    a0.x += a1.x; a0.y += a1.y; a0.z += a1.z; a0.w += a1.w;

    const float inv = (c > 0) ? 1.0f / (float)c : 0.0f;
    ushort4 o;
    o.x = f32_to_bf16(a0.x * inv);
    o.y = f32_to_bf16(a0.y * inv);
    o.z = f32_to_bf16(a0.z * inv);
    o.w = f32_to_bf16(a0.w * inv);
    agg[(size_t)g * 16 + lane - (isUser ? 0 : (size_t)N_USER * 16)] = o;
}

// ---------------------------------------------------------------------------
// Kernel 5: final dual GEMM, 64 rows/block, 4x4 register tile per thread.
// out = agg@W + b_et*[cnt>0] + feat@loop + h_bias. LDS padded [64][65].
// ---------------------------------------------------------------------------
__global__ __launch_bounds__(256) void final_gemm(
    const ushort4* __restrict__ aggB, const float* __restrict__ feat,
    const int* __restrict__ cntG,
    const float* __restrict__ W, const float* __restrict__ loop_w,
    const float* __restrict__ b_et, const float* __restrict__ h_bias,
    float* __restrict__ outN, int nrows)
{
    __shared__ float sW[64][65];
    __shared__ float sL[64][65];
    __shared__ float sA[64][65];
    __shared__ float sF[64][65];
    __shared__ float sbe[64], sbh[64];
    __shared__ int scnt[64];
    const int tid = threadIdx.x;
    const int row0 = blockIdx.x * 64;

    for (int i = tid; i < 4096; i += 256) {
        int k = i >> 6, cc = i & 63;
        sW[k][cc] = W[i];
        sL[k][cc] = loop_w[i];
    }
    if (tid < 64) { sbe[tid] = b_et[tid]; sbh[tid] = h_bias[tid]; }
    // stage agg rows (bf16 -> fp32)
    for (int i = tid; i < 1024; i += 256) {
        int row = i >> 4, q = i & 15;
        int r = row0 + row;
        ushort4 u = (r < nrows) ? aggB[(size_t)r * 16 + q] : make_ushort4(0, 0, 0, 0);
        sA[row][q * 4 + 0] = bf16_to_f32(u.x);
        sA[row][q * 4 + 1] = bf16_to_f32(u.y);
        sA[row][q * 4 + 2] = bf16_to_f32(u.z);
        sA[row][q * 4 + 3] = bf16_to_f32(u.w);
    }
    for (int i = tid; i < 4096; i += 256) {
        int row = i >> 6, k = i & 63;
        int r = row0 + row;
        sF[row][k] = (r < nrows) ? feat[(size_t)r * D + k] : 0.0f;
    }
    if (tid < 64) {
        int r = row0 + tid;
        scnt[tid] = (r < nrows) ? cntG[r] : 0;
    }
    __syncthreads();

    const int tr = tid >> 4;     // row group: rows 4*tr .. 4*tr+3
    const int tc = tid & 15;     // col group: cols 4*tc .. 4*tc+3
    float a[4][4] = {};
    float l[4][4] = {};
    #pragma unroll
    for (int k = 0; k < 64; ++k) {
        float wv[4], lv[4], av[4], fv[4];
        #pragma unroll
        for (int j = 0; j < 4; ++j) { wv[j] = sW[k][tc * 4 + j]; lv[j] = sL[k][tc * 4 + j]; }
        #pragma unroll
        for (int i = 0; i < 4; ++i) { av[i] = sA[tr * 4 + i][k]; fv[i] = sF[tr * 4 + i][k]; }
        #pragma unroll
        for (int i = 0; i < 4; ++i)
            #pragma unroll
            for (int j = 0; j < 4; ++j) {
                a[i][j] += av[i] * wv[j];
                l[i][j] += fv[i] * lv[j];
            }
    }

    #pragma unroll
    for (int i = 0; i < 4; ++i) {
        int row = tr * 4 + i;
        int r = row0 + row;
        if (r < nrows) {
            float be_on = (scnt[row] > 0) ? 1.0f : 0.0f;
            float4 o;
            o.x = a[i][0] + l[i][0] + sbh[tc * 4 + 0] + be_on * sbe[tc * 4 + 0];
            o.y = a[i][1] + l[i][1] + sbh[tc * 4 + 1] + be_on * sbe[tc * 4 + 1];
            o.z = a[i][2] + l[i][2] + sbh[tc * 4 + 2] + be_on * sbe[tc * 4 + 2];
            o.w = a[i][3] + l[i][3] + sbh[tc * 4 + 3] + be_on * sbe[tc * 4 + 3];
            *(float4*)&outN[(size_t)r * D + tc * 4] = o;
        }
    }
}

// ---------------------------------------------------------------------------
extern "C" void kernel_launch(void* const* d_in, const int* in_sizes, int n_in,
                              void* d_out, int out_size, void* d_ws, size_t ws_size,
                              hipStream_t stream)
{
    const float* user_feat = (const float*)d_in[0];
    const float* item_feat = (const float*)d_in[1];
    const int*   rate_src  = (const int*)d_in[2];
    const int*   rate_dst  = (const int*)d_in[3];
    const int*   rev_src   = (const int*)d_in[4];
    const int*   rev_dst   = (const int*)d_in[5];
    const float* W_rate    = (const float*)d_in[6];
    const float* b_rate    = (const float*)d_in[7];
    const float* W_rev     = (const float*)d_in[8];
    const float* b_rev     = (const float*)d_in[9];
    const float* loop_w    = (const float*)d_in[10];
    const float* h_bias    = (const float*)d_in[11];
    float* out = (float*)d_out;

    // workspace layout (~51 MB)
    char* p = (char*)d_ws;
    ushort4* userB = (ushort4*)p; p += (size_t)N_USER * D * 2;                 // 6.4 MB
    ushort4* itemB = (ushort4*)p; p += (size_t)N_ITEM * D * 2;                 // 6.4 MB
    unsigned* binI = (unsigned*)p; p += (size_t)N_FINE * CAP * 4;              // 8.2 MB
    unsigned* binU = (unsigned*)p; p += (size_t)N_FINE * CAP * 4;              // 8.2 MB
    unsigned short* srtI = (unsigned short*)p; p += (size_t)N_FINE * CAP * 2;  // 4.1 MB
    unsigned short* srtU = (unsigned short*)p; p += (size_t)N_FINE * CAP * 2;  // 4.1 MB
    ushort4* aggI  = (ushort4*)p; p += (size_t)N_NODE * D * 2;                 // 6.4 MB
    ushort4* aggU  = (ushort4*)p; p += (size_t)N_NODE * D * 2;                 // 6.4 MB
    int* offI = (int*)p; p += (size_t)N_NODE * 4;
    int* offU = (int*)p; p += (size_t)N_NODE * 4;
    int* cntI = (int*)p; p += (size_t)N_NODE * 4;
    int* cntU = (int*)p; p += (size_t)N_NODE * 4;
    int* fcur = (int*)p; p += (size_t)(2 * N_FINE) * 4;
    (void)ws_size;

    // 0) bf16 feature tables + cursor init
    cast_kernel<<<3125, 256, 0, stream>>>((const float4*)user_feat, userB, N_USER * 16);
    cast_kernel<<<3125, 256, 0, stream>>>((const float4*)item_feat, itemB, N_ITEM * 16);
    init_fcur<<<1, 1024, 0, stream>>>(fcur);

    // 1) fine binning (multisplit into fixed-capacity bucket windows)
    fine_bin<<<dim3((N_EDGE + CHUNK - 1) / CHUNK, 2), 256, 0, stream>>>(
        rate_src, rate_dst, binI,
        rev_src,  rev_dst,  binU, fcur);

    // 2) per-bucket counting sort -> u16 srt + off/cnt
    bucket_sort<<<dim3(N_FINE, 2), 256, 0, stream>>>(
        binI, srtI, offI, cntI,
        binU, srtU, offU, cntU, fcur);

    // 3) raw-feature segment mean (bf16)
    aggregate_kernel<<<(N_USER + N_ITEM + 15) / 16, 256, 0, stream>>>(
        itemB, userB,
        offU, cntU, srtU,
        offI, cntI, srtI,
        aggU, aggI);

    // 4) final dual GEMMs (fully write d_out)
    final_gemm<<<(N_NODE + 63) / 64, 256, 0, stream>>>(
        aggU, user_feat, cntU, W_rev, loop_w, b_rev, h_bias,
        out, N_NODE);
    final_gemm<<<(N_NODE + 63) / 64, 256, 0, stream>>>(
        aggI, item_feat, cntI, W_rate, loop_w, b_rate, h_bias,
        out + (size_t)N_USER * D, N_NODE);

    (void)in_sizes; (void)n_in; (void)out_size;
}

// Round 7
// 441.828 us; speedup vs baseline: 2.6452x; 2.6452x over previous
//
#include <hip/hip_runtime.h>

#define N_USER 50000
#define N_ITEM 50000
#define N_NODE 50000
#define N_EDGE 1600000
#define D 64

#define FB_SHIFT 7        // 128 nodes per fine bucket
#define N_FINE 400        // covers 51200 >= 50000 nodes
#define CAP 5120          // per-bucket edge capacity (mean 4096, sigma 64 -> 16 sigma)
#define CHUNK 8192        // edges per fine_bin block

__device__ __forceinline__ unsigned short f32_to_bf16(float x) {
    unsigned u = __float_as_uint(x);
    unsigned r = (u + 0x7FFFu + ((u >> 16) & 1u)) >> 16;   // RNE
    return (unsigned short)r;
}
__device__ __forceinline__ float bf16_to_f32(unsigned short h) {
    return __uint_as_float(((unsigned)h) << 16);
}

// ---------------------------------------------------------------------------
// Kernel 0: fp32 -> bf16 feature table cast (halves gather traffic).
// ---------------------------------------------------------------------------
__global__ __launch_bounds__(256) void cast_kernel(
    const float4* __restrict__ in, ushort4* __restrict__ out, int n4)
{
    int i = blockIdx.x * 256 + threadIdx.x;
    if (i < n4) {
        float4 v = in[i];
        ushort4 o;
        o.x = f32_to_bf16(v.x); o.y = f32_to_bf16(v.y);
        o.z = f32_to_bf16(v.z); o.w = f32_to_bf16(v.w);
        out[i] = o;
    }
}

// ---------------------------------------------------------------------------
// Kernel 1: init per-bucket cursors to fixed bases f*CAP.
// ---------------------------------------------------------------------------
__global__ __launch_bounds__(1024) void init_fcur(int* __restrict__ fcur)
{
    int i = threadIdx.x;
    if (i < 2 * N_FINE) {
        int f = (i < N_FINE) ? i : i - N_FINE;
        fcur[i] = f * CAP;
    }
}

// ---------------------------------------------------------------------------
// Kernel 2: fine binning (multisplit). Count chunk in LDS, reserve one
// contiguous window per bucket, scatter packed (dst<<16)|src via LDS cursors.
// ---------------------------------------------------------------------------
__global__ __launch_bounds__(256) void fine_bin(
    const int* __restrict__ srcA, const int* __restrict__ dstA, unsigned* __restrict__ binA,
    const int* __restrict__ srcB, const int* __restrict__ dstB, unsigned* __restrict__ binB,
    int* __restrict__ fcur)
{
    const int et = blockIdx.y;
    const int* __restrict__ src = et ? srcB : srcA;
    const int* __restrict__ dst = et ? dstB : dstA;
    unsigned* __restrict__ bin  = et ? binB : binA;
    int* __restrict__ fc = fcur + et * N_FINE;

    __shared__ int hist[N_FINE];
    __shared__ int lcur[N_FINE];
    for (int i = threadIdx.x; i < N_FINE; i += 256) hist[i] = 0;
    __syncthreads();

    const int base = blockIdx.x * CHUNK;
    const int n4 = (min(CHUNK, N_EDGE - base)) >> 2;   // N_EDGE % 4 == 0
    const int4* dst4 = (const int4*)(dst + base);
    const int4* src4 = (const int4*)(src + base);

    for (int i = threadIdx.x; i < n4; i += 256) {
        int4 d = dst4[i];
        atomicAdd(&hist[d.x >> FB_SHIFT], 1);
        atomicAdd(&hist[d.y >> FB_SHIFT], 1);
        atomicAdd(&hist[d.z >> FB_SHIFT], 1);
        atomicAdd(&hist[d.w >> FB_SHIFT], 1);
    }
    __syncthreads();
    for (int f = threadIdx.x; f < N_FINE; f += 256) {
        int c = hist[f];
        lcur[f] = c ? atomicAdd(&fc[f], c) : 0;
    }
    __syncthreads();
    for (int i = threadIdx.x; i < n4; i += 256) {
        int4 d = dst4[i];
        int4 s = src4[i];
        { int pos = atomicAdd(&lcur[d.x >> FB_SHIFT], 1); bin[pos] = ((unsigned)d.x << 16) | (unsigned)s.x; }
        { int pos = atomicAdd(&lcur[d.y >> FB_SHIFT], 1); bin[pos] = ((unsigned)d.y << 16) | (unsigned)s.y; }
        { int pos = atomicAdd(&lcur[d.z >> FB_SHIFT], 1); bin[pos] = ((unsigned)d.z << 16) | (unsigned)s.z; }
        { int pos = atomicAdd(&lcur[d.w >> FB_SHIFT], 1); bin[pos] = ((unsigned)d.w << 16) | (unsigned)s.w; }
    }
}

// ---------------------------------------------------------------------------
// Kernel 3: per-bucket counting sort -> u16 srt + off/cnt. 1.5 KB LDS.
// ---------------------------------------------------------------------------
__global__ __launch_bounds__(256) void bucket_sort(
    const unsigned* __restrict__ binI, unsigned short* __restrict__ srtI,
    int* __restrict__ offI, int* __restrict__ cntI,
    const unsigned* __restrict__ binU, unsigned short* __restrict__ srtU,
    int* __restrict__ offU, int* __restrict__ cntU,
    const int* __restrict__ fcur)
{
    const int et = blockIdx.y;
    const unsigned* __restrict__ bin = et ? binU : binI;
    unsigned short* __restrict__ srt = et ? srtU : srtI;
    int* __restrict__ off  = et ? offU : offI;
    int* __restrict__ cntG = et ? cntU : cntI;
    const int f = blockIdx.x;
    const int start = f * CAP;
    const int end   = fcur[et * N_FINE + f];
    const int nodebase = f << FB_SHIFT;

    __shared__ int cnt[128];
    __shared__ int sc[128];
    __shared__ int pos[128];
    if (threadIdx.x < 128) cnt[threadIdx.x] = 0;
    __syncthreads();

    for (int e = start + threadIdx.x; e < end; e += 256) {
        int ld = (int)(bin[e] >> 16) - nodebase;
        atomicAdd(&cnt[ld], 1);
    }
    __syncthreads();

    if (threadIdx.x < 128) sc[threadIdx.x] = cnt[threadIdx.x];
    __syncthreads();
    for (int o = 1; o < 128; o <<= 1) {
        int t = 0;
        if (threadIdx.x < 128 && threadIdx.x >= o) t = sc[threadIdx.x - o];
        __syncthreads();
        if (threadIdx.x < 128) sc[threadIdx.x] += t;
        __syncthreads();
    }
    if (threadIdx.x < 128) {
        int base = start + sc[threadIdx.x] - cnt[threadIdx.x];   // absolute excl
        pos[threadIdx.x] = base;
        int node = nodebase + threadIdx.x;
        if (node < N_NODE) { off[node] = base; cntG[node] = cnt[threadIdx.x]; }
    }
    __syncthreads();

    for (int e = start + threadIdx.x; e < end; e += 256) {
        unsigned p = bin[e];
        int ld = (int)(p >> 16) - nodebase;
        int q = atomicAdd(&pos[ld], 1);
        srt[q] = (unsigned short)(p & 0xFFFFu);
    }
}

// ---------------------------------------------------------------------------
// Kernel 4: raw-feature segment mean (bf16 gather). No LDS, 16 lanes/node,
// ushort4 per lane (128 B per edge), unroll-2.
// ---------------------------------------------------------------------------
__global__ __launch_bounds__(256) void aggregate_kernel(
    const ushort4* __restrict__ itemB,   // sources for user dst (rev)
    const ushort4* __restrict__ userB,   // sources for item dst (rate)
    const int* __restrict__ offU, const int* __restrict__ cntU, const unsigned short* __restrict__ srtU,
    const int* __restrict__ offI, const int* __restrict__ cntI, const unsigned short* __restrict__ srtI,
    ushort4* __restrict__ aggU, ushort4* __restrict__ aggI)
{
    int g = blockIdx.x * 16 + (threadIdx.x >> 4);
    if (g >= N_USER + N_ITEM) return;
    const int lane = threadIdx.x & 15;

    const bool isUser = (g < N_USER);
    const int d = isUser ? g : g - N_USER;
    const ushort4* __restrict__ tab = isUser ? itemB : userB;
    const int* __restrict__ off     = isUser ? offU : offI;
    const int* __restrict__ cntG    = isUser ? cntU : cntI;
    const unsigned short* __restrict__ srt = isUser ? srtU : srtI;
    ushort4* __restrict__ agg       = isUser ? aggU : aggI;

    const int start = off[d];
    const int c     = cntG[d];
    const int end   = start + c;

    float4 a0 = make_float4(0.f, 0.f, 0.f, 0.f);
    float4 a1 = make_float4(0.f, 0.f, 0.f, 0.f);
    int e = start;
    for (; e + 2 <= end; e += 2) {
        int s0 = (int)srt[e], s1 = (int)srt[e + 1];
        ushort4 w0 = tab[(size_t)s0 * 16 + lane];
        ushort4 w1 = tab[(size_t)s1 * 16 + lane];
        a0.x += bf16_to_f32(w0.x); a0.y += bf16_to_f32(w0.y);
        a0.z += bf16_to_f32(w0.z); a0.w += bf16_to_f32(w0.w);
        a1.x += bf16_to_f32(w1.x); a1.y += bf16_to_f32(w1.y);
        a1.z += bf16_to_f32(w1.z); a1.w += bf16_to_f32(w1.w);
    }
    if (e < end) {
        int s0 = (int)srt[e];
        ushort4 w0 = tab[(size_t)s0 * 16 + lane];
        a0.x += bf16_to_f32(w0.x); a0.y += bf16_to_f32(w0.y);
        a0.z += bf16_to_f32(w0.z); a0.w += bf16_to_f32(w0.w);
    }
    a0.x += a1.x; a0.y += a1.y; a0.z += a1.z; a0.w += a1.w;

    const float inv = (c > 0) ? 1.0f / (float)c : 0.0f;
    ushort4 o;
    o.x = f32_to_bf16(a0.x * inv);
    o.y = f32_to_bf16(a0.y * inv);
    o.z = f32_to_bf16(a0.z * inv);
    o.w = f32_to_bf16(a0.w * inv);
    agg[(size_t)g * 16 + lane - (isUser ? 0 : (size_t)N_USER * 16)] = o;
}

// ---------------------------------------------------------------------------
// Kernel 5: final dual GEMM, round-1 proven shape: 16 rows/block, each
// thread owns 1 col x 4 rows for both products (agg@W and feat@loop).
// out = agg@W + b_et*[cnt>0] + feat@loop + h_bias.
// Low VGPR, ~41 KB LDS — this shape never surfaced in top-5 in rounds 1-4.
// ---------------------------------------------------------------------------
__global__ __launch_bounds__(256) void final_gemm(
    const ushort4* __restrict__ aggB, const float* __restrict__ feat,
    const int* __restrict__ cntG,
    const float* __restrict__ W, const float* __restrict__ loop_w,
    const float* __restrict__ b_et, const float* __restrict__ h_bias,
    float* __restrict__ outN, int nrows)
{
    __shared__ float sW[64][64];
    __shared__ float sL[64][64];
    __shared__ float sA[16][64];
    __shared__ float sF[16][64];
    __shared__ float sbe[64], sbh[64];
    __shared__ int scnt[16];
    const int tid = threadIdx.x;

    for (int i = tid; i < 4096; i += 256) {
        sW[i >> 6][i & 63] = W[i];
        sL[i >> 6][i & 63] = loop_w[i];
    }
    if (tid < 64) { sbe[tid] = b_et[tid]; sbh[tid] = h_bias[tid]; }

    const int row0 = blockIdx.x * 16;
    // stage agg rows (bf16 -> fp32): thread tid covers row tid>>4, quad tid&15
    {
        int row = tid >> 4, q = tid & 15;
        int r = row0 + row;
        ushort4 u = (r < nrows) ? aggB[(size_t)r * 16 + q] : make_ushort4(0, 0, 0, 0);
        sA[row][q * 4 + 0] = bf16_to_f32(u.x);
        sA[row][q * 4 + 1] = bf16_to_f32(u.y);
        sA[row][q * 4 + 2] = bf16_to_f32(u.z);
        sA[row][q * 4 + 3] = bf16_to_f32(u.w);
    }
    for (int i = tid; i < 1024; i += 256) {
        int r = row0 + (i >> 6);
        sF[i >> 6][i & 63] = (r < nrows) ? feat[(size_t)r * D + (i & 63)] : 0.0f;
    }
    if (tid < 16) {
        int r = row0 + tid;
        scnt[tid] = (r < nrows) ? cntG[r] : 0;
    }
    __syncthreads();

    const int c = tid & 63;   // output column
    const int r = tid >> 6;   // local rows r, r+4, r+8, r+12
    float a0 = 0.f, a1 = 0.f, a2 = 0.f, a3 = 0.f;   // agg @ W
    float l0 = 0.f, l1 = 0.f, l2 = 0.f, l3 = 0.f;   // feat @ loop
    #pragma unroll
    for (int k = 0; k < 64; ++k) {
        float w = sW[k][c], l = sL[k][c];
        float q0 = sA[r][k], q1 = sA[r + 4][k], q2 = sA[r + 8][k], q3 = sA[r + 12][k];
        float f0 = sF[r][k], f1 = sF[r + 4][k], f2 = sF[r + 8][k], f3 = sF[r + 12][k];
        a0 += q0 * w; a1 += q1 * w; a2 += q2 * w; a3 += q3 * w;
        l0 += f0 * l; l1 += f1 * l; l2 += f2 * l; l3 += f3 * l;
    }
    const float be = sbe[c], bh = sbh[c];
    int rr;
    rr = row0 + r;      if (rr < nrows) outN[(size_t)rr * D + c] = a0 + l0 + bh + (scnt[r]      > 0 ? be : 0.f);
    rr = row0 + r + 4;  if (rr < nrows) outN[(size_t)rr * D + c] = a1 + l1 + bh + (scnt[r + 4]  > 0 ? be : 0.f);
    rr = row0 + r + 8;  if (rr < nrows) outN[(size_t)rr * D + c] = a2 + l2 + bh + (scnt[r + 8]  > 0 ? be : 0.f);
    rr = row0 + r + 12; if (rr < nrows) outN[(size_t)rr * D + c] = a3 + l3 + bh + (scnt[r + 12] > 0 ? be : 0.f);
}

// ---------------------------------------------------------------------------
extern "C" void kernel_launch(void* const* d_in, const int* in_sizes, int n_in,
                              void* d_out, int out_size, void* d_ws, size_t ws_size,
                              hipStream_t stream)
{
    const float* user_feat = (const float*)d_in[0];
    const float* item_feat = (const float*)d_in[1];
    const int*   rate_src  = (const int*)d_in[2];
    const int*   rate_dst  = (const int*)d_in[3];
    const int*   rev_src   = (const int*)d_in[4];
    const int*   rev_dst   = (const int*)d_in[5];
    const float* W_rate    = (const float*)d_in[6];
    const float* b_rate    = (const float*)d_in[7];
    const float* W_rev     = (const float*)d_in[8];
    const float* b_rev     = (const float*)d_in[9];
    const float* loop_w    = (const float*)d_in[10];
    const float* h_bias    = (const float*)d_in[11];
    float* out = (float*)d_out;

    // workspace layout (~51 MB)
    char* p = (char*)d_ws;
    ushort4* userB = (ushort4*)p; p += (size_t)N_USER * D * 2;                 // 6.4 MB
    ushort4* itemB = (ushort4*)p; p += (size_t)N_ITEM * D * 2;                 // 6.4 MB
    unsigned* binI = (unsigned*)p; p += (size_t)N_FINE * CAP * 4;              // 8.2 MB
    unsigned* binU = (unsigned*)p; p += (size_t)N_FINE * CAP * 4;              // 8.2 MB
    unsigned short* srtI = (unsigned short*)p; p += (size_t)N_FINE * CAP * 2;  // 4.1 MB
    unsigned short* srtU = (unsigned short*)p; p += (size_t)N_FINE * CAP * 2;  // 4.1 MB
    ushort4* aggI  = (ushort4*)p; p += (size_t)N_NODE * D * 2;                 // 6.4 MB
    ushort4* aggU  = (ushort4*)p; p += (size_t)N_NODE * D * 2;                 // 6.4 MB
    int* offI = (int*)p; p += (size_t)N_NODE * 4;
    int* offU = (int*)p; p += (size_t)N_NODE * 4;
    int* cntI = (int*)p; p += (size_t)N_NODE * 4;
    int* cntU = (int*)p; p += (size_t)N_NODE * 4;
    int* fcur = (int*)p; p += (size_t)(2 * N_FINE) * 4;
    (void)ws_size;

    // 0) bf16 feature tables + cursor init
    cast_kernel<<<3125, 256, 0, stream>>>((const float4*)user_feat, userB, N_USER * 16);
    cast_kernel<<<3125, 256, 0, stream>>>((const float4*)item_feat, itemB, N_ITEM * 16);
    init_fcur<<<1, 1024, 0, stream>>>(fcur);

    // 1) fine binning (multisplit into fixed-capacity bucket windows)
    fine_bin<<<dim3((N_EDGE + CHUNK - 1) / CHUNK, 2), 256, 0, stream>>>(
        rate_src, rate_dst, binI,
        rev_src,  rev_dst,  binU, fcur);

    // 2) per-bucket counting sort -> u16 srt + off/cnt
    bucket_sort<<<dim3(N_FINE, 2), 256, 0, stream>>>(
        binI, srtI, offI, cntI,
        binU, srtU, offU, cntU, fcur);

    // 3) raw-feature segment mean (bf16)
    aggregate_kernel<<<(N_USER + N_ITEM + 15) / 16, 256, 0, stream>>>(
        itemB, userB,
        offU, cntU, srtU,
        offI, cntI, srtI,
        aggU, aggI);

    // 4) final dual GEMMs (fully write d_out)
    final_gemm<<<(N_NODE + 15) / 16, 256, 0, stream>>>(
        aggU, user_feat, cntU, W_rev, loop_w, b_rev, h_bias,
        out, N_NODE);
    final_gemm<<<(N_NODE + 15) / 16, 256, 0, stream>>>(
        aggI, item_feat, cntI, W_rate, loop_w, b_rate, h_bias,
        out + (size_t)N_USER * D, N_NODE);

    (void)in_sizes; (void)n_in; (void)out_size;
}

// Round 8
// 291.542 us; speedup vs baseline: 4.0088x; 1.5155x over previous
//
#include <hip/hip_runtime.h>

#define N_USER 50000
#define N_ITEM 50000
#define N_NODE 50000
#define N_EDGE 1600000
#define D 64

#define FB_SHIFT 7        // 128 nodes per fine bucket
#define N_FINE 400        // covers 51200 >= 50000 nodes
#define CAP 5120          // per-bucket edge capacity (mean 4096, sigma 64 -> 16 sigma)
#define CHUNK 8192        // edges per fine_bin block

__device__ __forceinline__ unsigned short f32_to_bf16(float x) {
    unsigned u = __float_as_uint(x);
    unsigned r = (u + 0x7FFFu + ((u >> 16) & 1u)) >> 16;   // RNE
    return (unsigned short)r;
}
__device__ __forceinline__ float bf16_to_f32(unsigned short h) {
    return __uint_as_float(((unsigned)h) << 16);
}

// ---------------------------------------------------------------------------
// Kernel 0: fp32 -> bf16 feature table cast (halves gather traffic).
// One merged launch: y=0 users, y=1 items.
// ---------------------------------------------------------------------------
__global__ __launch_bounds__(256) void cast_kernel(
    const float4* __restrict__ inU, ushort4* __restrict__ outU,
    const float4* __restrict__ inI, ushort4* __restrict__ outI, int n4)
{
    const float4* __restrict__ in = blockIdx.y ? inI : inU;
    ushort4* __restrict__ out     = blockIdx.y ? outI : outU;
    int i = blockIdx.x * 256 + threadIdx.x;
    if (i < n4) {
        float4 v = in[i];
        ushort4 o;
        o.x = f32_to_bf16(v.x); o.y = f32_to_bf16(v.y);
        o.z = f32_to_bf16(v.z); o.w = f32_to_bf16(v.w);
        out[i] = o;
    }
}

// ---------------------------------------------------------------------------
// Kernel 1: init per-bucket cursors to fixed bases f*CAP.
// ---------------------------------------------------------------------------
__global__ __launch_bounds__(1024) void init_fcur(int* __restrict__ fcur)
{
    int i = threadIdx.x;
    if (i < 2 * N_FINE) {
        int f = (i < N_FINE) ? i : i - N_FINE;
        fcur[i] = f * CAP;
    }
}

// ---------------------------------------------------------------------------
// Kernel 2: fine binning (multisplit). Count chunk in LDS, reserve one
// contiguous window per bucket, scatter packed (dst<<16)|src via LDS cursors.
// ---------------------------------------------------------------------------
__global__ __launch_bounds__(256) void fine_bin(
    const int* __restrict__ srcA, const int* __restrict__ dstA, unsigned* __restrict__ binA,
    const int* __restrict__ srcB, const int* __restrict__ dstB, unsigned* __restrict__ binB,
    int* __restrict__ fcur)
{
    const int et = blockIdx.y;
    const int* __restrict__ src = et ? srcB : srcA;
    const int* __restrict__ dst = et ? dstB : dstA;
    unsigned* __restrict__ bin  = et ? binB : binA;
    int* __restrict__ fc = fcur + et * N_FINE;

    __shared__ int hist[N_FINE];
    __shared__ int lcur[N_FINE];
    for (int i = threadIdx.x; i < N_FINE; i += 256) hist[i] = 0;
    __syncthreads();

    const int base = blockIdx.x * CHUNK;
    const int n4 = (min(CHUNK, N_EDGE - base)) >> 2;   // N_EDGE % 4 == 0
    const int4* dst4 = (const int4*)(dst + base);
    const int4* src4 = (const int4*)(src + base);

    for (int i = threadIdx.x; i < n4; i += 256) {
        int4 d = dst4[i];
        atomicAdd(&hist[d.x >> FB_SHIFT], 1);
        atomicAdd(&hist[d.y >> FB_SHIFT], 1);
        atomicAdd(&hist[d.z >> FB_SHIFT], 1);
        atomicAdd(&hist[d.w >> FB_SHIFT], 1);
    }
    __syncthreads();
    for (int f = threadIdx.x; f < N_FINE; f += 256) {
        int c = hist[f];
        lcur[f] = c ? atomicAdd(&fc[f], c) : 0;
    }
    __syncthreads();
    for (int i = threadIdx.x; i < n4; i += 256) {
        int4 d = dst4[i];
        int4 s = src4[i];
        { int pos = atomicAdd(&lcur[d.x >> FB_SHIFT], 1); bin[pos] = ((unsigned)d.x << 16) | (unsigned)s.x; }
        { int pos = atomicAdd(&lcur[d.y >> FB_SHIFT], 1); bin[pos] = ((unsigned)d.y << 16) | (unsigned)s.y; }
        { int pos = atomicAdd(&lcur[d.z >> FB_SHIFT], 1); bin[pos] = ((unsigned)d.z << 16) | (unsigned)s.z; }
        { int pos = atomicAdd(&lcur[d.w >> FB_SHIFT], 1); bin[pos] = ((unsigned)d.w << 16) | (unsigned)s.w; }
    }
}

// ---------------------------------------------------------------------------
// Kernel 3: per-bucket counting sort -> u16 srt + off/cnt. 1.5 KB LDS.
// ---------------------------------------------------------------------------
__global__ __launch_bounds__(256) void bucket_sort(
    const unsigned* __restrict__ binI, unsigned short* __restrict__ srtI,
    int* __restrict__ offI, int* __restrict__ cntI,
    const unsigned* __restrict__ binU, unsigned short* __restrict__ srtU,
    int* __restrict__ offU, int* __restrict__ cntU,
    const int* __restrict__ fcur)
{
    const int et = blockIdx.y;
    const unsigned* __restrict__ bin = et ? binU : binI;
    unsigned short* __restrict__ srt = et ? srtU : srtI;
    int* __restrict__ off  = et ? offU : offI;
    int* __restrict__ cntG = et ? cntU : cntI;
    const int f = blockIdx.x;
    const int start = f * CAP;
    const int end   = fcur[et * N_FINE + f];
    const int nodebase = f << FB_SHIFT;

    __shared__ int cnt[128];
    __shared__ int sc[128];
    __shared__ int pos[128];
    if (threadIdx.x < 128) cnt[threadIdx.x] = 0;
    __syncthreads();

    for (int e = start + threadIdx.x; e < end; e += 256) {
        int ld = (int)(bin[e] >> 16) - nodebase;
        atomicAdd(&cnt[ld], 1);
    }
    __syncthreads();

    if (threadIdx.x < 128) sc[threadIdx.x] = cnt[threadIdx.x];
    __syncthreads();
    for (int o = 1; o < 128; o <<= 1) {
        int t = 0;
        if (threadIdx.x < 128 && threadIdx.x >= o) t = sc[threadIdx.x - o];
        __syncthreads();
        if (threadIdx.x < 128) sc[threadIdx.x] += t;
        __syncthreads();
    }
    if (threadIdx.x < 128) {
        int base = start + sc[threadIdx.x] - cnt[threadIdx.x];   // absolute excl
        pos[threadIdx.x] = base;
        int node = nodebase + threadIdx.x;
        if (node < N_NODE) { off[node] = base; cntG[node] = cnt[threadIdx.x]; }
    }
    __syncthreads();

    for (int e = start + threadIdx.x; e < end; e += 256) {
        unsigned p = bin[e];
        int ld = (int)(p >> 16) - nodebase;
        int q = atomicAdd(&pos[ld], 1);
        srt[q] = (unsigned short)(p & 0xFFFFu);
    }
}

// ---------------------------------------------------------------------------
// Kernel 4: raw-feature segment mean (bf16 gather). No LDS, 16 lanes/node,
// ushort4 per lane (128 B per edge), unroll-2.
// ---------------------------------------------------------------------------
__global__ __launch_bounds__(256) void aggregate_kernel(
    const ushort4* __restrict__ itemB,   // sources for user dst (rev)
    const ushort4* __restrict__ userB,   // sources for item dst (rate)
    const int* __restrict__ offU, const int* __restrict__ cntU, const unsigned short* __restrict__ srtU,
    const int* __restrict__ offI, const int* __restrict__ cntI, const unsigned short* __restrict__ srtI,
    ushort4* __restrict__ aggU, ushort4* __restrict__ aggI)
{
    int g = blockIdx.x * 16 + (threadIdx.x >> 4);
    if (g >= N_USER + N_ITEM) return;
    const int lane = threadIdx.x & 15;

    const bool isUser = (g < N_USER);
    const int d = isUser ? g : g - N_USER;
    const ushort4* __restrict__ tab = isUser ? itemB : userB;
    const int* __restrict__ off     = isUser ? offU : offI;
    const int* __restrict__ cntG    = isUser ? cntU : cntI;
    const unsigned short* __restrict__ srt = isUser ? srtU : srtI;
    ushort4* __restrict__ agg       = isUser ? aggU : aggI;

    const int start = off[d];
    const int c     = cntG[d];
    const int end   = start + c;

    float4 a0 = make_float4(0.f, 0.f, 0.f, 0.f);
    float4 a1 = make_float4(0.f, 0.f, 0.f, 0.f);
    int e = start;
    for (; e + 2 <= end; e += 2) {
        int s0 = (int)srt[e], s1 = (int)srt[e + 1];
        ushort4 w0 = tab[(size_t)s0 * 16 + lane];
        ushort4 w1 = tab[(size_t)s1 * 16 + lane];
        a0.x += bf16_to_f32(w0.x); a0.y += bf16_to_f32(w0.y);
        a0.z += bf16_to_f32(w0.z); a0.w += bf16_to_f32(w0.w);
        a1.x += bf16_to_f32(w1.x); a1.y += bf16_to_f32(w1.y);
        a1.z += bf16_to_f32(w1.z); a1.w += bf16_to_f32(w1.w);
    }
    if (e < end) {
        int s0 = (int)srt[e];
        ushort4 w0 = tab[(size_t)s0 * 16 + lane];
        a0.x += bf16_to_f32(w0.x); a0.y += bf16_to_f32(w0.y);
        a0.z += bf16_to_f32(w0.z); a0.w += bf16_to_f32(w0.w);
    }
    a0.x += a1.x; a0.y += a1.y; a0.z += a1.z; a0.w += a1.w;

    const float inv = (c > 0) ? 1.0f / (float)c : 0.0f;
    ushort4 o;
    o.x = f32_to_bf16(a0.x * inv);
    o.y = f32_to_bf16(a0.y * inv);
    o.z = f32_to_bf16(a0.z * inv);
    o.w = f32_to_bf16(a0.w * inv);
    agg[(size_t)g * 16 + lane - (isUser ? 0 : (size_t)N_USER * 16)] = o;
}

// ---------------------------------------------------------------------------
// Kernel 5: final dual GEMM, 16 rows/block, 1 col x 4 rows per thread for
// both products. __launch_bounds__(256,4) caps VGPR at 128 (round-7 counters
// showed 256 VGPR + 27 MB scratch-spill writes at full unroll); unroll 4
// keeps the live set ~50 VGPR. Merged launch: y=0 users, y=1 items.
// ---------------------------------------------------------------------------
__global__ __launch_bounds__(256, 4) void final_gemm(
    const ushort4* __restrict__ aggU_, const float* __restrict__ featU,
    const int* __restrict__ cntU_, const float* __restrict__ WU,
    const float* __restrict__ beU,
    const ushort4* __restrict__ aggI_, const float* __restrict__ featI,
    const int* __restrict__ cntI_, const float* __restrict__ WI,
    const float* __restrict__ beI,
    const float* __restrict__ loop_w, const float* __restrict__ h_bias,
    float* __restrict__ out)
{
    const int et = blockIdx.y;
    const ushort4* __restrict__ aggB = et ? aggI_ : aggU_;
    const float* __restrict__ feat   = et ? featI : featU;
    const int* __restrict__ cntG     = et ? cntI_ : cntU_;
    const float* __restrict__ W      = et ? WI : WU;
    const float* __restrict__ b_et   = et ? beI : beU;
    float* __restrict__ outN = out + (et ? (size_t)N_USER * D : 0);

    __shared__ float sW[64][64];
    __shared__ float sL[64][64];
    __shared__ float sA[16][64];
    __shared__ float sF[16][64];
    __shared__ float sbe[64], sbh[64];
    __shared__ int scnt[16];
    const int tid = threadIdx.x;

    for (int i = tid; i < 4096; i += 256) {
        sW[i >> 6][i & 63] = W[i];
        sL[i >> 6][i & 63] = loop_w[i];
    }
    if (tid < 64) { sbe[tid] = b_et[tid]; sbh[tid] = h_bias[tid]; }

    const int row0 = blockIdx.x * 16;
    {
        int row = tid >> 4, q = tid & 15;
        int r = row0 + row;
        ushort4 u = (r < N_NODE) ? aggB[(size_t)r * 16 + q] : make_ushort4(0, 0, 0, 0);
        sA[row][q * 4 + 0] = bf16_to_f32(u.x);
        sA[row][q * 4 + 1] = bf16_to_f32(u.y);
        sA[row][q * 4 + 2] = bf16_to_f32(u.z);
        sA[row][q * 4 + 3] = bf16_to_f32(u.w);
    }
    for (int i = tid; i < 1024; i += 256) {
        int r = row0 + (i >> 6);
        sF[i >> 6][i & 63] = (r < N_NODE) ? feat[(size_t)r * D + (i & 63)] : 0.0f;
    }
    if (tid < 16) {
        int r = row0 + tid;
        scnt[tid] = (r < N_NODE) ? cntG[r] : 0;
    }
    __syncthreads();

    const int c = tid & 63;   // output column
    const int r = tid >> 6;   // local rows r, r+4, r+8, r+12
    float a0 = 0.f, a1 = 0.f, a2 = 0.f, a3 = 0.f;   // agg @ W
    float l0 = 0.f, l1 = 0.f, l2 = 0.f, l3 = 0.f;   // feat @ loop
    #pragma unroll 4
    for (int k = 0; k < 64; ++k) {
        float w = sW[k][c], l = sL[k][c];
        float q0 = sA[r][k], q1 = sA[r + 4][k], q2 = sA[r + 8][k], q3 = sA[r + 12][k];
        float f0 = sF[r][k], f1 = sF[r + 4][k], f2 = sF[r + 8][k], f3 = sF[r + 12][k];
        a0 += q0 * w; a1 += q1 * w; a2 += q2 * w; a3 += q3 * w;
        l0 += f0 * l; l1 += f1 * l; l2 += f2 * l; l3 += f3 * l;
    }
    const float be = sbe[c], bh = sbh[c];
    int rr;
    rr = row0 + r;      if (rr < N_NODE) outN[(size_t)rr * D + c] = a0 + l0 + bh + (scnt[r]      > 0 ? be : 0.f);
    rr = row0 + r + 4;  if (rr < N_NODE) outN[(size_t)rr * D + c] = a1 + l1 + bh + (scnt[r + 4]  > 0 ? be : 0.f);
    rr = row0 + r + 8;  if (rr < N_NODE) outN[(size_t)rr * D + c] = a2 + l2 + bh + (scnt[r + 8]  > 0 ? be : 0.f);
    rr = row0 + r + 12; if (rr < N_NODE) outN[(size_t)rr * D + c] = a3 + l3 + bh + (scnt[r + 12] > 0 ? be : 0.f);
}

// ---------------------------------------------------------------------------
extern "C" void kernel_launch(void* const* d_in, const int* in_sizes, int n_in,
                              void* d_out, int out_size, void* d_ws, size_t ws_size,
                              hipStream_t stream)
{
    const float* user_feat = (const float*)d_in[0];
    const float* item_feat = (const float*)d_in[1];
    const int*   rate_src  = (const int*)d_in[2];
    const int*   rate_dst  = (const int*)d_in[3];
    const int*   rev_src   = (const int*)d_in[4];
    const int*   rev_dst   = (const int*)d_in[5];
    const float* W_rate    = (const float*)d_in[6];
    const float* b_rate    = (const float*)d_in[7];
    const float* W_rev     = (const float*)d_in[8];
    const float* b_rev     = (const float*)d_in[9];
    const float* loop_w    = (const float*)d_in[10];
    const float* h_bias    = (const float*)d_in[11];
    float* out = (float*)d_out;

    // workspace layout (~51 MB)
    char* p = (char*)d_ws;
    ushort4* userB = (ushort4*)p; p += (size_t)N_USER * D * 2;                 // 6.4 MB
    ushort4* itemB = (ushort4*)p; p += (size_t)N_ITEM * D * 2;                 // 6.4 MB
    unsigned* binI = (unsigned*)p; p += (size_t)N_FINE * CAP * 4;              // 8.2 MB
    unsigned* binU = (unsigned*)p; p += (size_t)N_FINE * CAP * 4;              // 8.2 MB
    unsigned short* srtI = (unsigned short*)p; p += (size_t)N_FINE * CAP * 2;  // 4.1 MB
    unsigned short* srtU = (unsigned short*)p; p += (size_t)N_FINE * CAP * 2;  // 4.1 MB
    ushort4* aggI  = (ushort4*)p; p += (size_t)N_NODE * D * 2;                 // 6.4 MB
    ushort4* aggU  = (ushort4*)p; p += (size_t)N_NODE * D * 2;                 // 6.4 MB
    int* offI = (int*)p; p += (size_t)N_NODE * 4;
    int* offU = (int*)p; p += (size_t)N_NODE * 4;
    int* cntI = (int*)p; p += (size_t)N_NODE * 4;
    int* cntU = (int*)p; p += (size_t)N_NODE * 4;
    int* fcur = (int*)p; p += (size_t)(2 * N_FINE) * 4;
    (void)ws_size;

    // 0) bf16 feature tables (merged) + cursor init
    cast_kernel<<<dim3(3125, 2), 256, 0, stream>>>(
        (const float4*)user_feat, userB, (const float4*)item_feat, itemB, N_NODE * 16);
    init_fcur<<<1, 1024, 0, stream>>>(fcur);

    // 1) fine binning (multisplit into fixed-capacity bucket windows)
    fine_bin<<<dim3((N_EDGE + CHUNK - 1) / CHUNK, 2), 256, 0, stream>>>(
        rate_src, rate_dst, binI,
        rev_src,  rev_dst,  binU, fcur);

    // 2) per-bucket counting sort -> u16 srt + off/cnt
    bucket_sort<<<dim3(N_FINE, 2), 256, 0, stream>>>(
        binI, srtI, offI, cntI,
        binU, srtU, offU, cntU, fcur);

    // 3) raw-feature segment mean (bf16)
    aggregate_kernel<<<(N_USER + N_ITEM + 15) / 16, 256, 0, stream>>>(
        itemB, userB,
        offU, cntU, srtU,
        offI, cntI, srtI,
        aggU, aggI);

    // 4) final dual GEMM (merged, fully writes d_out)
    final_gemm<<<dim3((N_NODE + 15) / 16, 2), 256, 0, stream>>>(
        aggU, user_feat, cntU, W_rev, b_rev,
        aggI, item_feat, cntI, W_rate, b_rate,
        loop_w, h_bias, out);

    (void)in_sizes; (void)n_in; (void)out_size;
}

// Round 9
// 240.192 us; speedup vs baseline: 4.8659x; 1.2138x over previous
//
#include <hip/hip_runtime.h>

#define N_USER 50000
#define N_ITEM 50000
#define N_NODE 50000
#define N_EDGE 1600000
#define D 64

#define FB_SHIFT 7        // 128 nodes per fine bucket
#define N_FINE 400        // covers 51200 >= 50000 nodes
#define CAP 5120          // per-bucket edge capacity (mean 4096, sigma 64 -> 16 sigma)
#define CHUNK 8192        // edges per fine_bin block

typedef __attribute__((ext_vector_type(8))) short short8;    // 8 bf16 = 4 VGPR
typedef __attribute__((ext_vector_type(4))) float floatx4;   // mfma acc

__device__ __forceinline__ unsigned short f32_to_bf16(float x) {
    unsigned u = __float_as_uint(x);
    unsigned r = (u + 0x7FFFu + ((u >> 16) & 1u)) >> 16;   // RNE
    return (unsigned short)r;
}
__device__ __forceinline__ float bf16_to_f32(unsigned short h) {
    return __uint_as_float(((unsigned)h) << 16);
}

// ---------------------------------------------------------------------------
// Kernel 0: fp32 -> bf16 feature table cast. y=0 users, y=1 items.
// ---------------------------------------------------------------------------
__global__ __launch_bounds__(256) void cast_kernel(
    const float4* __restrict__ inU, ushort4* __restrict__ outU,
    const float4* __restrict__ inI, ushort4* __restrict__ outI, int n4)
{
    const float4* __restrict__ in = blockIdx.y ? inI : inU;
    ushort4* __restrict__ out     = blockIdx.y ? outI : outU;
    int i = blockIdx.x * 256 + threadIdx.x;
    if (i < n4) {
        float4 v = in[i];
        ushort4 o;
        o.x = f32_to_bf16(v.x); o.y = f32_to_bf16(v.y);
        o.z = f32_to_bf16(v.z); o.w = f32_to_bf16(v.w);
        out[i] = o;
    }
}

// ---------------------------------------------------------------------------
// Kernel 1: init per-bucket cursors to fixed bases f*CAP.
// ---------------------------------------------------------------------------
__global__ __launch_bounds__(1024) void init_fcur(int* __restrict__ fcur)
{
    int i = threadIdx.x;
    if (i < 2 * N_FINE) {
        int f = (i < N_FINE) ? i : i - N_FINE;
        fcur[i] = f * CAP;
    }
}

// ---------------------------------------------------------------------------
// Kernel 2: fine binning (multisplit). Count chunk in LDS, reserve one
// contiguous window per bucket, scatter packed (dst<<16)|src via LDS cursors.
// ---------------------------------------------------------------------------
__global__ __launch_bounds__(256) void fine_bin(
    const int* __restrict__ srcA, const int* __restrict__ dstA, unsigned* __restrict__ binA,
    const int* __restrict__ srcB, const int* __restrict__ dstB, unsigned* __restrict__ binB,
    int* __restrict__ fcur)
{
    const int et = blockIdx.y;
    const int* __restrict__ src = et ? srcB : srcA;
    const int* __restrict__ dst = et ? dstB : dstA;
    unsigned* __restrict__ bin  = et ? binB : binA;
    int* __restrict__ fc = fcur + et * N_FINE;

    __shared__ int hist[N_FINE];
    __shared__ int lcur[N_FINE];
    for (int i = threadIdx.x; i < N_FINE; i += 256) hist[i] = 0;
    __syncthreads();

    const int base = blockIdx.x * CHUNK;
    const int n4 = (min(CHUNK, N_EDGE - base)) >> 2;   // N_EDGE % 4 == 0
    const int4* dst4 = (const int4*)(dst + base);
    const int4* src4 = (const int4*)(src + base);

    for (int i = threadIdx.x; i < n4; i += 256) {
        int4 d = dst4[i];
        atomicAdd(&hist[d.x >> FB_SHIFT], 1);
        atomicAdd(&hist[d.y >> FB_SHIFT], 1);
        atomicAdd(&hist[d.z >> FB_SHIFT], 1);
        atomicAdd(&hist[d.w >> FB_SHIFT], 1);
    }
    __syncthreads();
    for (int f = threadIdx.x; f < N_FINE; f += 256) {
        int c = hist[f];
        lcur[f] = c ? atomicAdd(&fc[f], c) : 0;
    }
    __syncthreads();
    for (int i = threadIdx.x; i < n4; i += 256) {
        int4 d = dst4[i];
        int4 s = src4[i];
        { int pos = atomicAdd(&lcur[d.x >> FB_SHIFT], 1); bin[pos] = ((unsigned)d.x << 16) | (unsigned)s.x; }
        { int pos = atomicAdd(&lcur[d.y >> FB_SHIFT], 1); bin[pos] = ((unsigned)d.y << 16) | (unsigned)s.y; }
        { int pos = atomicAdd(&lcur[d.z >> FB_SHIFT], 1); bin[pos] = ((unsigned)d.z << 16) | (unsigned)s.z; }
        { int pos = atomicAdd(&lcur[d.w >> FB_SHIFT], 1); bin[pos] = ((unsigned)d.w << 16) | (unsigned)s.w; }
    }
}

// ---------------------------------------------------------------------------
// Kernel 3: per-bucket counting sort -> u16 srt + off/cnt. 1.5 KB LDS.
// ---------------------------------------------------------------------------
__global__ __launch_bounds__(256) void bucket_sort(
    const unsigned* __restrict__ binI, unsigned short* __restrict__ srtI,
    int* __restrict__ offI, int* __restrict__ cntI,
    const unsigned* __restrict__ binU, unsigned short* __restrict__ srtU,
    int* __restrict__ offU, int* __restrict__ cntU,
    const int* __restrict__ fcur)
{
    const int et = blockIdx.y;
    const unsigned* __restrict__ bin = et ? binU : binI;
    unsigned short* __restrict__ srt = et ? srtU : srtI;
    int* __restrict__ off  = et ? offU : offI;
    int* __restrict__ cntG = et ? cntU : cntI;
    const int f = blockIdx.x;
    const int start = f * CAP;
    const int end   = fcur[et * N_FINE + f];
    const int nodebase = f << FB_SHIFT;

    __shared__ int cnt[128];
    __shared__ int sc[128];
    __shared__ int pos[128];
    if (threadIdx.x < 128) cnt[threadIdx.x] = 0;
    __syncthreads();

    for (int e = start + threadIdx.x; e < end; e += 256) {
        int ld = (int)(bin[e] >> 16) - nodebase;
        atomicAdd(&cnt[ld], 1);
    }
    __syncthreads();

    if (threadIdx.x < 128) sc[threadIdx.x] = cnt[threadIdx.x];
    __syncthreads();
    for (int o = 1; o < 128; o <<= 1) {
        int t = 0;
        if (threadIdx.x < 128 && threadIdx.x >= o) t = sc[threadIdx.x - o];
        __syncthreads();
        if (threadIdx.x < 128) sc[threadIdx.x] += t;
        __syncthreads();
    }
    if (threadIdx.x < 128) {
        int base = start + sc[threadIdx.x] - cnt[threadIdx.x];   // absolute excl
        pos[threadIdx.x] = base;
        int node = nodebase + threadIdx.x;
        if (node < N_NODE) { off[node] = base; cntG[node] = cnt[threadIdx.x]; }
    }
    __syncthreads();

    for (int e = start + threadIdx.x; e < end; e += 256) {
        unsigned p = bin[e];
        int ld = (int)(p >> 16) - nodebase;
        int q = atomicAdd(&pos[ld], 1);
        srt[q] = (unsigned short)(p & 0xFFFFu);
    }
}

// ---------------------------------------------------------------------------
// Kernel 4: raw-feature segment mean (bf16 gather). No LDS, 16 lanes/node,
// ushort4 per lane (128 B per edge), unroll-2.
// ---------------------------------------------------------------------------
__global__ __launch_bounds__(256) void aggregate_kernel(
    const ushort4* __restrict__ itemB,   // sources for user dst (rev)
    const ushort4* __restrict__ userB,   // sources for item dst (rate)
    const int* __restrict__ offU, const int* __restrict__ cntU, const unsigned short* __restrict__ srtU,
    const int* __restrict__ offI, const int* __restrict__ cntI, const unsigned short* __restrict__ srtI,
    ushort4* __restrict__ aggU, ushort4* __restrict__ aggI)
{
    int g = blockIdx.x * 16 + (threadIdx.x >> 4);
    if (g >= N_USER + N_ITEM) return;
    const int lane = threadIdx.x & 15;

    const bool isUser = (g < N_USER);
    const int d = isUser ? g : g - N_USER;
    const ushort4* __restrict__ tab = isUser ? itemB : userB;
    const int* __restrict__ off     = isUser ? offU : offI;
    const int* __restrict__ cntG    = isUser ? cntU : cntI;
    const unsigned short* __restrict__ srt = isUser ? srtU : srtI;
    ushort4* __restrict__ agg       = isUser ? aggU : aggI;

    const int start = off[d];
    const int c     = cntG[d];
    const int end   = start + c;

    float4 a0 = make_float4(0.f, 0.f, 0.f, 0.f);
    float4 a1 = make_float4(0.f, 0.f, 0.f, 0.f);
    int e = start;
    for (; e + 2 <= end; e += 2) {
        int s0 = (int)srt[e], s1 = (int)srt[e + 1];
        ushort4 w0 = tab[(size_t)s0 * 16 + lane];
        ushort4 w1 = tab[(size_t)s1 * 16 + lane];
        a0.x += bf16_to_f32(w0.x); a0.y += bf16_to_f32(w0.y);
        a0.z += bf16_to_f32(w0.z); a0.w += bf16_to_f32(w0.w);
        a1.x += bf16_to_f32(w1.x); a1.y += bf16_to_f32(w1.y);
        a1.z += bf16_to_f32(w1.z); a1.w += bf16_to_f32(w1.w);
    }
    if (e < end) {
        int s0 = (int)srt[e];
        ushort4 w0 = tab[(size_t)s0 * 16 + lane];
        a0.x += bf16_to_f32(w0.x); a0.y += bf16_to_f32(w0.y);
        a0.z += bf16_to_f32(w0.z); a0.w += bf16_to_f32(w0.w);
    }
    a0.x += a1.x; a0.y += a1.y; a0.z += a1.z; a0.w += a1.w;

    const float inv = (c > 0) ? 1.0f / (float)c : 0.0f;
    ushort4 o;
    o.x = f32_to_bf16(a0.x * inv);
    o.y = f32_to_bf16(a0.y * inv);
    o.z = f32_to_bf16(a0.z * inv);
    o.w = f32_to_bf16(a0.w * inv);
    agg[(size_t)g * 16 + lane - (isUser ? 0 : (size_t)N_USER * 16)] = o;
}

// ---------------------------------------------------------------------------
// Kernel 5: final dual GEMM via MFMA (16x16x32 bf16). 64 rows/block, 4 waves,
// wave w owns rows [w*16, w*16+16) x all 64 cols. Both products chain into
// one accumulator: D = agg@W + feat@loop (+ biases in epilogue).
// Layouts (guide-verified): A[m=lane&15][k=quad*8+j]; B[k=quad*8+j][n=lane&15];
// D col=lane&15, row=quad*4+reg. Weights bf16-transposed in LDS, row stride
// 72 bf16 (144 B) -> b128 reads are 2-way on banks = free.
// ---------------------------------------------------------------------------
__global__ __launch_bounds__(256, 4) void final_gemm(
    const unsigned short* __restrict__ aggU_, const unsigned short* __restrict__ featU_,
    const int* __restrict__ cntU_, const float* __restrict__ WU,
    const float* __restrict__ beU,
    const unsigned short* __restrict__ aggI_, const unsigned short* __restrict__ featI_,
    const int* __restrict__ cntI_, const float* __restrict__ WI,
    const float* __restrict__ beI,
    const float* __restrict__ loop_w, const float* __restrict__ h_bias,
    float* __restrict__ out)
{
    const int et = blockIdx.y;
    const unsigned short* __restrict__ agg  = et ? aggI_ : aggU_;
    const unsigned short* __restrict__ feat = et ? featI_ : featU_;
    const int* __restrict__ cntG            = et ? cntI_ : cntU_;
    const float* __restrict__ W             = et ? WI : WU;
    const float* __restrict__ b_et          = et ? beI : beU;
    float* __restrict__ outN = out + (et ? (size_t)N_USER * D : 0);

    __shared__ unsigned short sWt[64][72];   // W^T bf16:   sWt[n][k]
    __shared__ unsigned short sLt[64][72];   // loop^T bf16
    __shared__ float sbe[64], sbh[64];
    __shared__ int sCnt[64];

    const int tid = threadIdx.x;
    const int row0 = blockIdx.x * 64;

    for (int i = tid; i < 4096; i += 256) {
        int k = i >> 6, n = i & 63;
        sWt[n][k] = f32_to_bf16(W[i]);        // W[k][n]
        sLt[n][k] = f32_to_bf16(loop_w[i]);
    }
    if (tid < 64) {
        sbe[tid] = b_et[tid];
        sbh[tid] = h_bias[tid];
        int r = row0 + tid;
        sCnt[tid] = (r < N_NODE) ? cntG[r] : 0;
    }
    __syncthreads();

    const int wave = tid >> 6;
    const int lane = tid & 63;
    const int quad = lane >> 4;
    const int l16  = lane & 15;

    // a-fragments: row m = l16 (within wave's 16-row tile), k = h*32 + quad*8 + j
    const int rowA = row0 + wave * 16 + l16;
    const int rA = (rowA < N_NODE) ? rowA : (N_NODE - 1);
    short8 aAgg0  = *(const short8*)(agg  + (size_t)rA * 64 +      quad * 8);
    short8 aAgg1  = *(const short8*)(agg  + (size_t)rA * 64 + 32 + quad * 8);
    short8 aFeat0 = *(const short8*)(feat + (size_t)rA * 64 +      quad * 8);
    short8 aFeat1 = *(const short8*)(feat + (size_t)rA * 64 + 32 + quad * 8);

    floatx4 acc[4];
    #pragma unroll
    for (int t = 0; t < 4; ++t) {
        const int n = t * 16 + l16;
        short8 bW0 = *(const short8*)&sWt[n][     quad * 8];
        short8 bW1 = *(const short8*)&sWt[n][32 + quad * 8];
        short8 bL0 = *(const short8*)&sLt[n][     quad * 8];
        short8 bL1 = *(const short8*)&sLt[n][32 + quad * 8];
        floatx4 a = {0.f, 0.f, 0.f, 0.f};
        a = __builtin_amdgcn_mfma_f32_16x16x32_bf16(aAgg0,  bW0, a, 0, 0, 0);
        a = __builtin_amdgcn_mfma_f32_16x16x32_bf16(aAgg1,  bW1, a, 0, 0, 0);
        a = __builtin_amdgcn_mfma_f32_16x16x32_bf16(aFeat0, bL0, a, 0, 0, 0);
        a = __builtin_amdgcn_mfma_f32_16x16x32_bf16(aFeat1, bL1, a, 0, 0, 0);
        acc[t] = a;
    }

    #pragma unroll
    for (int t = 0; t < 4; ++t) {
        const int col = t * 16 + l16;
        const float bh = sbh[col], be = sbe[col];
        #pragma unroll
        for (int i = 0; i < 4; ++i) {
            int lrow = wave * 16 + quad * 4 + i;
            int r = row0 + lrow;
            if (r < N_NODE) {
                float v = acc[t][i] + bh + (sCnt[lrow] > 0 ? be : 0.f);
                outN[(size_t)r * D + col] = v;
            }
        }
    }
}

// ---------------------------------------------------------------------------
extern "C" void kernel_launch(void* const* d_in, const int* in_sizes, int n_in,
                              void* d_out, int out_size, void* d_ws, size_t ws_size,
                              hipStream_t stream)
{
    const float* user_feat = (const float*)d_in[0];
    const float* item_feat = (const float*)d_in[1];
    const int*   rate_src  = (const int*)d_in[2];
    const int*   rate_dst  = (const int*)d_in[3];
    const int*   rev_src   = (const int*)d_in[4];
    const int*   rev_dst   = (const int*)d_in[5];
    const float* W_rate    = (const float*)d_in[6];
    const float* b_rate    = (const float*)d_in[7];
    const float* W_rev     = (const float*)d_in[8];
    const float* b_rev     = (const float*)d_in[9];
    const float* loop_w    = (const float*)d_in[10];
    const float* h_bias    = (const float*)d_in[11];
    float* out = (float*)d_out;

    // workspace layout (~51 MB)
    char* p = (char*)d_ws;
    ushort4* userB = (ushort4*)p; p += (size_t)N_USER * D * 2;                 // 6.4 MB
    ushort4* itemB = (ushort4*)p; p += (size_t)N_ITEM * D * 2;                 // 6.4 MB
    unsigned* binI = (unsigned*)p; p += (size_t)N_FINE * CAP * 4;              // 8.2 MB
    unsigned* binU = (unsigned*)p; p += (size_t)N_FINE * CAP * 4;              // 8.2 MB
    unsigned short* srtI = (unsigned short*)p; p += (size_t)N_FINE * CAP * 2;  // 4.1 MB
    unsigned short* srtU = (unsigned short*)p; p += (size_t)N_FINE * CAP * 2;  // 4.1 MB
    ushort4* aggI  = (ushort4*)p; p += (size_t)N_NODE * D * 2;                 // 6.4 MB
    ushort4* aggU  = (ushort4*)p; p += (size_t)N_NODE * D * 2;                 // 6.4 MB
    int* offI = (int*)p; p += (size_t)N_NODE * 4;
    int* offU = (int*)p; p += (size_t)N_NODE * 4;
    int* cntI = (int*)p; p += (size_t)N_NODE * 4;
    int* cntU = (int*)p; p += (size_t)N_NODE * 4;
    int* fcur = (int*)p; p += (size_t)(2 * N_FINE) * 4;
    (void)ws_size;

    // 0) bf16 feature tables (merged) + cursor init
    cast_kernel<<<dim3(3125, 2), 256, 0, stream>>>(
        (const float4*)user_feat, userB, (const float4*)item_feat, itemB, N_NODE * 16);
    init_fcur<<<1, 1024, 0, stream>>>(fcur);

    // 1) fine binning (multisplit into fixed-capacity bucket windows)
    fine_bin<<<dim3((N_EDGE + CHUNK - 1) / CHUNK, 2), 256, 0, stream>>>(
        rate_src, rate_dst, binI,
        rev_src,  rev_dst,  binU, fcur);

    // 2) per-bucket counting sort -> u16 srt + off/cnt
    bucket_sort<<<dim3(N_FINE, 2), 256, 0, stream>>>(
        binI, srtI, offI, cntI,
        binU, srtU, offU, cntU, fcur);

    // 3) raw-feature segment mean (bf16)
    aggregate_kernel<<<(N_USER + N_ITEM + 15) / 16, 256, 0, stream>>>(
        itemB, userB,
        offU, cntU, srtU,
        offI, cntI, srtI,
        aggU, aggI);

    // 4) final dual GEMM via MFMA (merged, fully writes d_out)
    final_gemm<<<dim3((N_NODE + 63) / 64, 2), 256, 0, stream>>>(
        (const unsigned short*)aggU, (const unsigned short*)userB, cntU, W_rev, b_rev,
        (const unsigned short*)aggI, (const unsigned short*)itemB, cntI, W_rate, b_rate,
        loop_w, h_bias, out);

    (void)in_sizes; (void)n_in; (void)out_size;
}

// Round 10
// 235.846 us; speedup vs baseline: 4.9555x; 1.0184x over previous
//
#include <hip/hip_runtime.h>

#define N_USER 50000
#define N_ITEM 50000
#define N_NODE 50000
#define N_EDGE 1600000
#define D 64

#define FB_SHIFT 7        // 128 nodes per fine bucket
#define N_FINE 400        // covers 51200 >= 50000 nodes
#define CAP 5120          // per-bucket edge capacity (mean 4096 -> 16 sigma headroom)
#define BIN_CHUNK 4096    // edges per bin block (2x parallelism vs 8192)
#define NCAST 3125        // cast blocks per table: 50000*16/256 exactly
#define NBIN ((N_EDGE + BIN_CHUNK - 1) / BIN_CHUNK)   // 391

typedef __attribute__((ext_vector_type(8))) short short8;    // 8 bf16 = 4 VGPR
typedef __attribute__((ext_vector_type(4))) float floatx4;   // mfma acc

__device__ __forceinline__ unsigned short f32_to_bf16(float x) {
    unsigned u = __float_as_uint(x);
    unsigned r = (u + 0x7FFFu + ((u >> 16) & 1u)) >> 16;   // RNE
    return (unsigned short)r;
}
__device__ __forceinline__ float bf16_to_f32(unsigned short h) {
    return __uint_as_float(((unsigned)h) << 16);
}

// ---------------------------------------------------------------------------
// Kernel 1 (merged): blocks [0,NCAST) cast fp32->bf16 feature tables;
// blocks [NCAST, NCAST+NBIN) run fine binning (multisplit into fixed-capacity
// bucket windows). y = etype/table. fcur holds per-bucket COUNTS (memset 0);
// window base is f*CAP added at reservation.
// ---------------------------------------------------------------------------
__global__ __launch_bounds__(256) void cast_bin(
    const float4* __restrict__ fU, ushort4* __restrict__ bU,
    const float4* __restrict__ fI, ushort4* __restrict__ bI,
    const int* __restrict__ srcA, const int* __restrict__ dstA, unsigned* __restrict__ binA,
    const int* __restrict__ srcB, const int* __restrict__ dstB, unsigned* __restrict__ binB,
    int* __restrict__ fcur)
{
    __shared__ int hist[N_FINE];
    __shared__ int lcur[N_FINE];
    const int et = blockIdx.y;

    if (blockIdx.x < NCAST) {
        // cast role: pure streaming, exact bounds (NCAST*256 == N_NODE*16)
        const float4* __restrict__ in = et ? fI : fU;
        ushort4* __restrict__ out     = et ? bI : bU;
        int i = blockIdx.x * 256 + threadIdx.x;
        float4 v = in[i];
        ushort4 o;
        o.x = f32_to_bf16(v.x); o.y = f32_to_bf16(v.y);
        o.z = f32_to_bf16(v.z); o.w = f32_to_bf16(v.w);
        out[i] = o;
        return;
    }

    // fine_bin role
    const int* __restrict__ src = et ? srcB : srcA;
    const int* __restrict__ dst = et ? dstB : dstA;
    unsigned* __restrict__ bin  = et ? binB : binA;
    int* __restrict__ fc = fcur + et * N_FINE;

    for (int i = threadIdx.x; i < N_FINE; i += 256) hist[i] = 0;
    __syncthreads();

    const int chunk = blockIdx.x - NCAST;
    const int base = chunk * BIN_CHUNK;
    const int n4 = (min(BIN_CHUNK, N_EDGE - base)) >> 2;   // N_EDGE % 4 == 0
    const int4* dst4 = (const int4*)(dst + base);
    const int4* src4 = (const int4*)(src + base);

    // pass 1: count
    for (int i = threadIdx.x; i < n4; i += 256) {
        int4 d = dst4[i];
        atomicAdd(&hist[d.x >> FB_SHIFT], 1);
        atomicAdd(&hist[d.y >> FB_SHIFT], 1);
        atomicAdd(&hist[d.z >> FB_SHIFT], 1);
        atomicAdd(&hist[d.w >> FB_SHIFT], 1);
    }
    __syncthreads();
    // reserve contiguous windows (base f*CAP + running count)
    for (int f = threadIdx.x; f < N_FINE; f += 256) {
        int c = hist[f];
        lcur[f] = c ? (f * CAP + atomicAdd(&fc[f], c)) : 0;
    }
    __syncthreads();
    // pass 2: scatter packed (dst<<16)|src
    for (int i = threadIdx.x; i < n4; i += 256) {
        int4 d = dst4[i];
        int4 s = src4[i];
        { int pos = atomicAdd(&lcur[d.x >> FB_SHIFT], 1); bin[pos] = ((unsigned)d.x << 16) | (unsigned)s.x; }
        { int pos = atomicAdd(&lcur[d.y >> FB_SHIFT], 1); bin[pos] = ((unsigned)d.y << 16) | (unsigned)s.y; }
        { int pos = atomicAdd(&lcur[d.z >> FB_SHIFT], 1); bin[pos] = ((unsigned)d.z << 16) | (unsigned)s.z; }
        { int pos = atomicAdd(&lcur[d.w >> FB_SHIFT], 1); bin[pos] = ((unsigned)d.w << 16) | (unsigned)s.w; }
    }
}

// ---------------------------------------------------------------------------
// Kernel 2: per-bucket counting sort -> u16 srt + off/cnt. 1.5 KB LDS.
// ---------------------------------------------------------------------------
__global__ __launch_bounds__(256) void bucket_sort(
    const unsigned* __restrict__ binI, unsigned short* __restrict__ srtI,
    int* __restrict__ offI, int* __restrict__ cntI,
    const unsigned* __restrict__ binU, unsigned short* __restrict__ srtU,
    int* __restrict__ offU, int* __restrict__ cntU,
    const int* __restrict__ fcur)
{
    const int et = blockIdx.y;
    const unsigned* __restrict__ bin = et ? binU : binI;
    unsigned short* __restrict__ srt = et ? srtU : srtI;
    int* __restrict__ off  = et ? offU : offI;
    int* __restrict__ cntG = et ? cntU : cntI;
    const int f = blockIdx.x;
    const int start = f * CAP;
    const int end   = start + fcur[et * N_FINE + f];   // fcur now holds counts
    const int nodebase = f << FB_SHIFT;

    __shared__ int cnt[128];
    __shared__ int sc[128];
    __shared__ int pos[128];
    if (threadIdx.x < 128) cnt[threadIdx.x] = 0;
    __syncthreads();

    for (int e = start + threadIdx.x; e < end; e += 256) {
        int ld = (int)(bin[e] >> 16) - nodebase;
        atomicAdd(&cnt[ld], 1);
    }
    __syncthreads();

    if (threadIdx.x < 128) sc[threadIdx.x] = cnt[threadIdx.x];
    __syncthreads();
    for (int o = 1; o < 128; o <<= 1) {
        int t = 0;
        if (threadIdx.x < 128 && threadIdx.x >= o) t = sc[threadIdx.x - o];
        __syncthreads();
        if (threadIdx.x < 128) sc[threadIdx.x] += t;
        __syncthreads();
    }
    if (threadIdx.x < 128) {
        int base = start + sc[threadIdx.x] - cnt[threadIdx.x];   // absolute excl
        pos[threadIdx.x] = base;
        int node = nodebase + threadIdx.x;
        if (node < N_NODE) { off[node] = base; cntG[node] = cnt[threadIdx.x]; }
    }
    __syncthreads();

    for (int e = start + threadIdx.x; e < end; e += 256) {
        unsigned p = bin[e];
        int ld = (int)(p >> 16) - nodebase;
        int q = atomicAdd(&pos[ld], 1);
        srt[q] = (unsigned short)(p & 0xFFFFu);
    }
}

// ---------------------------------------------------------------------------
// Kernel 3: raw-feature segment mean (bf16 gather). No LDS, 16 lanes/node,
// ushort4 per lane (128 B per edge), unroll-4 for memory-level parallelism.
// ---------------------------------------------------------------------------
__global__ __launch_bounds__(256) void aggregate_kernel(
    const ushort4* __restrict__ itemB,   // sources for user dst (rev)
    const ushort4* __restrict__ userB,   // sources for item dst (rate)
    const int* __restrict__ offU, const int* __restrict__ cntU, const unsigned short* __restrict__ srtU,
    const int* __restrict__ offI, const int* __restrict__ cntI, const unsigned short* __restrict__ srtI,
    ushort4* __restrict__ aggU, ushort4* __restrict__ aggI)
{
    int g = blockIdx.x * 16 + (threadIdx.x >> 4);
    if (g >= N_USER + N_ITEM) return;
    const int lane = threadIdx.x & 15;

    const bool isUser = (g < N_USER);
    const int d = isUser ? g : g - N_USER;
    const ushort4* __restrict__ tab = isUser ? itemB : userB;
    const int* __restrict__ off     = isUser ? offU : offI;
    const int* __restrict__ cntG    = isUser ? cntU : cntI;
    const unsigned short* __restrict__ srt = isUser ? srtU : srtI;
    ushort4* __restrict__ agg       = isUser ? aggU : aggI;

    const int start = off[d];
    const int c     = cntG[d];
    const int end   = start + c;

    float4 a0 = make_float4(0.f, 0.f, 0.f, 0.f);
    float4 a1 = make_float4(0.f, 0.f, 0.f, 0.f);
    float4 a2 = make_float4(0.f, 0.f, 0.f, 0.f);
    float4 a3 = make_float4(0.f, 0.f, 0.f, 0.f);
    int e = start;
    for (; e + 4 <= end; e += 4) {
        int s0 = (int)srt[e],     s1 = (int)srt[e + 1];
        int s2 = (int)srt[e + 2], s3 = (int)srt[e + 3];
        ushort4 w0 = tab[(size_t)s0 * 16 + lane];
        ushort4 w1 = tab[(size_t)s1 * 16 + lane];
        ushort4 w2 = tab[(size_t)s2 * 16 + lane];
        ushort4 w3 = tab[(size_t)s3 * 16 + lane];
        a0.x += bf16_to_f32(w0.x); a0.y += bf16_to_f32(w0.y);
        a0.z += bf16_to_f32(w0.z); a0.w += bf16_to_f32(w0.w);
        a1.x += bf16_to_f32(w1.x); a1.y += bf16_to_f32(w1.y);
        a1.z += bf16_to_f32(w1.z); a1.w += bf16_to_f32(w1.w);
        a2.x += bf16_to_f32(w2.x); a2.y += bf16_to_f32(w2.y);
        a2.z += bf16_to_f32(w2.z); a2.w += bf16_to_f32(w2.w);
        a3.x += bf16_to_f32(w3.x); a3.y += bf16_to_f32(w3.y);
        a3.z += bf16_to_f32(w3.z); a3.w += bf16_to_f32(w3.w);
    }
    for (; e < end; ++e) {
        int s0 = (int)srt[e];
        ushort4 w0 = tab[(size_t)s0 * 16 + lane];
        a0.x += bf16_to_f32(w0.x); a0.y += bf16_to_f32(w0.y);
        a0.z += bf16_to_f32(w0.z); a0.w += bf16_to_f32(w0.w);
    }
    a0.x += a1.x + a2.x + a3.x;
    a0.y += a1.y + a2.y + a3.y;
    a0.z += a1.z + a2.z + a3.z;
    a0.w += a1.w + a2.w + a3.w;

    const float inv = (c > 0) ? 1.0f / (float)c : 0.0f;
    ushort4 o;
    o.x = f32_to_bf16(a0.x * inv);
    o.y = f32_to_bf16(a0.y * inv);
    o.z = f32_to_bf16(a0.z * inv);
    o.w = f32_to_bf16(a0.w * inv);
    agg[(size_t)g * 16 + lane - (isUser ? 0 : (size_t)N_USER * 16)] = o;
}

// ---------------------------------------------------------------------------
// Kernel 4: final dual GEMM via MFMA (16x16x32 bf16). 64 rows/block, 4 waves.
// D = agg@W + feat@loop (+ biases in epilogue). Layouts guide-verified.
// ---------------------------------------------------------------------------
__global__ __launch_bounds__(256, 4) void final_gemm(
    const unsigned short* __restrict__ aggU_, const unsigned short* __restrict__ featU_,
    const int* __restrict__ cntU_, const float* __restrict__ WU,
    const float* __restrict__ beU,
    const unsigned short* __restrict__ aggI_, const unsigned short* __restrict__ featI_,
    const int* __restrict__ cntI_, const float* __restrict__ WI,
    const float* __restrict__ beI,
    const float* __restrict__ loop_w, const float* __restrict__ h_bias,
    float* __restrict__ out)
{
    const int et = blockIdx.y;
    const unsigned short* __restrict__ agg  = et ? aggI_ : aggU_;
    const unsigned short* __restrict__ feat = et ? featI_ : featU_;
    const int* __restrict__ cntG            = et ? cntI_ : cntU_;
    const float* __restrict__ W             = et ? WI : WU;
    const float* __restrict__ b_et          = et ? beI : beU;
    float* __restrict__ outN = out + (et ? (size_t)N_USER * D : 0);

    __shared__ unsigned short sWt[64][72];   // W^T bf16:   sWt[n][k]
    __shared__ unsigned short sLt[64][72];   // loop^T bf16
    __shared__ float sbe[64], sbh[64];
    __shared__ int sCnt[64];

    const int tid = threadIdx.x;
    const int row0 = blockIdx.x * 64;

    for (int i = tid; i < 4096; i += 256) {
        int k = i >> 6, n = i & 63;
        sWt[n][k] = f32_to_bf16(W[i]);        // W[k][n]
        sLt[n][k] = f32_to_bf16(loop_w[i]);
    }
    if (tid < 64) {
        sbe[tid] = b_et[tid];
        sbh[tid] = h_bias[tid];
        int r = row0 + tid;
        sCnt[tid] = (r < N_NODE) ? cntG[r] : 0;
    }
    __syncthreads();

    const int wave = tid >> 6;
    const int lane = tid & 63;
    const int quad = lane >> 4;
    const int l16  = lane & 15;

    const int rowA = row0 + wave * 16 + l16;
    const int rA = (rowA < N_NODE) ? rowA : (N_NODE - 1);
    short8 aAgg0  = *(const short8*)(agg  + (size_t)rA * 64 +      quad * 8);
    short8 aAgg1  = *(const short8*)(agg  + (size_t)rA * 64 + 32 + quad * 8);
    short8 aFeat0 = *(const short8*)(feat + (size_t)rA * 64 +      quad * 8);
    short8 aFeat1 = *(const short8*)(feat + (size_t)rA * 64 + 32 + quad * 8);

    floatx4 acc[4];
    #pragma unroll
    for (int t = 0; t < 4; ++t) {
        const int n = t * 16 + l16;
        short8 bW0 = *(const short8*)&sWt[n][     quad * 8];
        short8 bW1 = *(const short8*)&sWt[n][32 + quad * 8];
        short8 bL0 = *(const short8*)&sLt[n][     quad * 8];
        short8 bL1 = *(const short8*)&sLt[n][32 + quad * 8];
        floatx4 a = {0.f, 0.f, 0.f, 0.f};
        a = __builtin_amdgcn_mfma_f32_16x16x32_bf16(aAgg0,  bW0, a, 0, 0, 0);
        a = __builtin_amdgcn_mfma_f32_16x16x32_bf16(aAgg1,  bW1, a, 0, 0, 0);
        a = __builtin_amdgcn_mfma_f32_16x16x32_bf16(aFeat0, bL0, a, 0, 0, 0);
        a = __builtin_amdgcn_mfma_f32_16x16x32_bf16(aFeat1, bL1, a, 0, 0, 0);
        acc[t] = a;
    }

    #pragma unroll
    for (int t = 0; t < 4; ++t) {
        const int col = t * 16 + l16;
        const float bh = sbh[col], be = sbe[col];
        #pragma unroll
        for (int i = 0; i < 4; ++i) {
            int lrow = wave * 16 + quad * 4 + i;
            int r = row0 + lrow;
            if (r < N_NODE) {
                float v = acc[t][i] + bh + (sCnt[lrow] > 0 ? be : 0.f);
                outN[(size_t)r * D + col] = v;
            }
        }
    }
}

// ---------------------------------------------------------------------------
extern "C" void kernel_launch(void* const* d_in, const int* in_sizes, int n_in,
                              void* d_out, int out_size, void* d_ws, size_t ws_size,
                              hipStream_t stream)
{
    const float* user_feat = (const float*)d_in[0];
    const float* item_feat = (const float*)d_in[1];
    const int*   rate_src  = (const int*)d_in[2];
    const int*   rate_dst  = (const int*)d_in[3];
    const int*   rev_src   = (const int*)d_in[4];
    const int*   rev_dst   = (const int*)d_in[5];
    const float* W_rate    = (const float*)d_in[6];
    const float* b_rate    = (const float*)d_in[7];
    const float* W_rev     = (const float*)d_in[8];
    const float* b_rev     = (const float*)d_in[9];
    const float* loop_w    = (const float*)d_in[10];
    const float* h_bias    = (const float*)d_in[11];
    float* out = (float*)d_out;

    // workspace layout (~51 MB)
    char* p = (char*)d_ws;
    ushort4* userB = (ushort4*)p; p += (size_t)N_USER * D * 2;                 // 6.4 MB
    ushort4* itemB = (ushort4*)p; p += (size_t)N_ITEM * D * 2;                 // 6.4 MB
    unsigned* binI = (unsigned*)p; p += (size_t)N_FINE * CAP * 4;              // 8.2 MB
    unsigned* binU = (unsigned*)p; p += (size_t)N_FINE * CAP * 4;              // 8.2 MB
    unsigned short* srtI = (unsigned short*)p; p += (size_t)N_FINE * CAP * 2;  // 4.1 MB
    unsigned short* srtU = (unsigned short*)p; p += (size_t)N_FINE * CAP * 2;  // 4.1 MB
    ushort4* aggI  = (ushort4*)p; p += (size_t)N_NODE * D * 2;                 // 6.4 MB
    ushort4* aggU  = (ushort4*)p; p += (size_t)N_NODE * D * 2;                 // 6.4 MB
    int* offI = (int*)p; p += (size_t)N_NODE * 4;
    int* offU = (int*)p; p += (size_t)N_NODE * 4;
    int* cntI = (int*)p; p += (size_t)N_NODE * 4;
    int* cntU = (int*)p; p += (size_t)N_NODE * 4;
    int* fcur = (int*)p; p += (size_t)(2 * N_FINE) * 4;
    (void)ws_size;

    // fcur = per-bucket counts, zero-init (3.2 KB)
    hipMemsetAsync(fcur, 0, (size_t)(2 * N_FINE) * sizeof(int), stream);

    // 1) merged cast (blocks [0,NCAST)) + fine binning (blocks [NCAST,NCAST+NBIN))
    cast_bin<<<dim3(NCAST + NBIN, 2), 256, 0, stream>>>(
        (const float4*)user_feat, userB, (const float4*)item_feat, itemB,
        rate_src, rate_dst, binI,
        rev_src,  rev_dst,  binU, fcur);

    // 2) per-bucket counting sort -> u16 srt + off/cnt
    bucket_sort<<<dim3(N_FINE, 2), 256, 0, stream>>>(
        binI, srtI, offI, cntI,
        binU, srtU, offU, cntU, fcur);

    // 3) raw-feature segment mean (bf16, unroll-4)
    aggregate_kernel<<<(N_USER + N_ITEM + 15) / 16, 256, 0, stream>>>(
        itemB, userB,
        offU, cntU, srtU,
        offI, cntI, srtI,
        aggU, aggI);

    // 4) final dual GEMM via MFMA (merged, fully writes d_out)
    final_gemm<<<dim3((N_NODE + 63) / 64, 2), 256, 0, stream>>>(
        (const unsigned short*)aggU, (const unsigned short*)userB, cntU, W_rev, b_rev,
        (const unsigned short*)aggI, (const unsigned short*)itemB, cntI, W_rate, b_rate,
        loop_w, h_bias, out);

    (void)in_sizes; (void)n_in; (void)out_size;
}